// Round 19
// baseline (327.955 us; speedup 1.0000x reference)
//
#include <hip/hip_runtime.h>
#include <hip/hip_bf16.h>
#include <cstdint>

#define B_Q    2048
#define N_K    131072
#define KD     256
#define VD     256
#define TOPK   8

#define TK     32                 // keys per tile
#define NCHUNK 64
#define CHUNK  (N_K / NCHUNK)     // 2048
#define CTILES (CHUNK / TK)       // 64
#define QB     128                // queries per phase-1 block (4 waves x 32 q)
#define QTILES (B_Q / QB)         // 16
#define QBS    256                // queries per sample block
#define NBUF   2
#define TILE_B (TK * KD * 2)      // 16384 B per permuted tile
#define SSTEPS 8                  // 256 / 32
#define SLOTS  32                 // per-(q,chunk) candidate slots
#define OVCAP  8192
#define NSUB   16                 // sample sub-blocks per query tile
#define TAU_MARGIN 2.0f
#define SENTF  0x7F800000u        // +INF bits

typedef short bf16x8 __attribute__((ext_vector_type(8)));
typedef float f32x4  __attribute__((ext_vector_type(4)));

__device__ __forceinline__ unsigned short f2bf(float x) {
    uint32_t u = __float_as_uint(x);
    uint32_t r = (u + 0x7FFFu + ((u >> 16) & 1u)) >> 16;
    return (unsigned short)r;
}

__device__ __forceinline__ bool lex_lt(float d1, int i1, float d2, int i2) {
    return (d1 < d2) || (d1 == d2 && i1 < i2);
}

__device__ __forceinline__ uint32_t umin32(uint32_t a, uint32_t b) { return a < b ? a : b; }
__device__ __forceinline__ uint32_t umax32(uint32_t a, uint32_t b) { return a > b ? a : b; }
__device__ __forceinline__ unsigned long long umin64(unsigned long long a, unsigned long long b) { return a < b ? a : b; }

__device__ __forceinline__ void gld16(const void* g, void* l) {
    __builtin_amdgcn_global_load_lds(
        (const __attribute__((address_space(1))) unsigned int*)g,
        (__attribute__((address_space(3))) unsigned int*)l, 16, 0, 0);
}
__device__ __forceinline__ void gld4(const void* g, void* l) {
    __builtin_amdgcn_global_load_lds(
        (const __attribute__((address_space(1))) unsigned int*)g,
        (__attribute__((address_space(3))) unsigned int*)l, 4, 0, 0);
}

__device__ __forceinline__ void ins8u(uint32_t v, uint32_t (&c)[8]) {
    if (v < c[7]) {
        c[7] = v;
        #pragma unroll
        for (int p = 7; p > 0; --p)
            if (c[p] < c[p - 1]) { uint32_t t = c[p]; c[p] = c[p - 1]; c[p - 1] = t; }
    }
}

// queries: q2 (exact) + augmented bf16 [-2q] rows
__global__ void qprep_kernel(const float* __restrict__ q, float* __restrict__ q2,
                             unsigned short* __restrict__ qa) {
    int gw   = (blockIdx.x * blockDim.x + threadIdx.x) >> 6;
    int lane = threadIdx.x & 63;
    float4 v = reinterpret_cast<const float4*>(q + (size_t)gw * KD)[lane];
    float s = v.x * v.x + v.y * v.y + v.z * v.z + v.w * v.w;
    #pragma unroll
    for (int off = 32; off > 0; off >>= 1) s += __shfl_down(s, off, 64);
    if (lane == 0) q2[gw] = s;
    ushort4 u;
    u.x = f2bf(-2.f * v.x); u.y = f2bf(-2.f * v.y);
    u.z = f2bf(-2.f * v.z); u.w = f2bf(-2.f * v.w);
    *reinterpret_cast<ushort4*>(qa + (size_t)gw * KD + lane * 4) = u;
}

// fused: keys -> k2 (exact row norms) + bf16 permuted MFMA fragment-stream.
__global__ __launch_bounds__(256) void kperm2_kernel(
    const float* __restrict__ keys, unsigned short* __restrict__ kp,
    float* __restrict__ k2) {
    __shared__ float psum[32][33];
    const int gt = blockIdx.x, tid = threadIdx.x;
    #pragma unroll
    for (int u = 0; u < 4; ++u) {
        int unit = u * 256 + tid;
        int row  = unit >> 5;
        int grp  = unit & 31;
        const float* src = keys + (size_t)(gt * 32 + row) * KD + grp * 8;
        float4 a = *reinterpret_cast<const float4*>(src);
        float4 b = *reinterpret_cast<const float4*>(src + 4);
        psum[row][grp] = a.x * a.x + a.y * a.y + a.z * a.z + a.w * a.w
                       + b.x * b.x + b.y * b.y + b.z * b.z + b.w * b.w;
        uint4 pack;
        pack.x = (uint32_t)f2bf(a.x) | ((uint32_t)f2bf(a.y) << 16);
        pack.y = (uint32_t)f2bf(a.z) | ((uint32_t)f2bf(a.w) << 16);
        pack.z = (uint32_t)f2bf(b.x) | ((uint32_t)f2bf(b.y) << 16);
        pack.w = (uint32_t)f2bf(b.z) | ((uint32_t)f2bf(b.w) << 16);
        int s  = grp >> 2;
        int ki = row >> 4;
        int l  = ((grp & 3) << 4) | (row & 15);
        size_t o = ((((size_t)gt * 8 + s) * 2 + ki) * 64 + l);
        *reinterpret_cast<uint4*>(kp + o * 8) = pack;
    }
    __syncthreads();
    if (tid < 32) {
        float s = 0.f;
        #pragma unroll
        for (int g = 0; g < 32; ++g) s += psum[tid][g];
        k2[gt * 32 + tid] = s;
    }
}

// sample: coarse scores (k2+256-2qk) of chunk-0 sub-range (4 tiles = 128 keys),
// per-query top-8 scores -> subtop[q][sub][8] (f32 bits, uint-monotone)
__global__ __launch_bounds__(512, 2) void sample_kernel(
    const unsigned short* __restrict__ qaug, const char* __restrict__ kperm,
    const float* __restrict__ k2, uint32_t* __restrict__ subtop) {

    __shared__ __align__(16) char  lds[TILE_B];
    __shared__ __align__(16) float k2l[64];

    const int tid = threadIdx.x;
    const int w   = tid >> 6;
    const int l   = tid & 63;
    const int l15 = l & 15;
    const int l4  = l >> 4;
    const int sub = blockIdx.x & (NSUB - 1);
    const int qt  = blockIdx.x >> 4;
    const int q0  = qt * QBS;

    bf16x8 af[2][SSTEPS];
    #pragma unroll
    for (int qf = 0; qf < 2; ++qf)
        #pragma unroll
        for (int s = 0; s < SSTEPS; ++s) {
            int qr = q0 + w * 32 + qf * 16 + l15;
            af[qf][s] = *reinterpret_cast<const bf16x8*>(
                qaug + (size_t)qr * KD + s * 32 + l4 * 8);
        }

    uint32_t cnd[2][4][8];
    #pragma unroll
    for (int qf = 0; qf < 2; ++qf)
        #pragma unroll
        for (int j = 0; j < 4; ++j)
            #pragma unroll
            for (int s = 0; s < 8; ++s) cnd[qf][j][s] = SENTF;

    for (int i = 0; i < 4; ++i) {
        int t = sub * 4 + i;
        __syncthreads();   // prior tile's reads done before overwrite
        const char* src = kperm + (size_t)t * TILE_B;   // chunk 0
        #pragma unroll
        for (int i2 = 0; i2 < 2; ++i2) {
            int seg = w * 2 + i2;
            gld16(src + seg * 1024 + l * 16, &lds[seg * 1024]);
        }
        gld4(k2 + t * TK + l, &k2l[0]);
        __syncthreads();   // drains vmcnt

        float k2v[2];
        #pragma unroll
        for (int ki = 0; ki < 2; ++ki) k2v[ki] = k2l[ki * 16 + l15] + 256.0f;

        f32x4 acc[2][2];
        #pragma unroll
        for (int qf = 0; qf < 2; ++qf)
            #pragma unroll
            for (int ki = 0; ki < 2; ++ki) acc[qf][ki] = (f32x4){0.f, 0.f, 0.f, 0.f};

        #pragma unroll
        for (int s = 0; s < SSTEPS; ++s) {
            bf16x8 bfr[2];
            #pragma unroll
            for (int ki = 0; ki < 2; ++ki)
                bfr[ki] = *reinterpret_cast<const bf16x8*>(&lds[((s * 2 + ki) * 64 + l) * 16]);
            #pragma unroll
            for (int ki = 0; ki < 2; ++ki) {
                acc[0][ki] = __builtin_amdgcn_mfma_f32_16x16x32_bf16(af[0][s], bfr[ki], acc[0][ki], 0, 0, 0);
                acc[1][ki] = __builtin_amdgcn_mfma_f32_16x16x32_bf16(af[1][s], bfr[ki], acc[1][ki], 0, 0, 0);
            }
        }

        #pragma unroll
        for (int qf = 0; qf < 2; ++qf)
            #pragma unroll
            for (int j = 0; j < 4; ++j) {
                ins8u(__float_as_uint(k2v[0] + acc[qf][0][j]), cnd[qf][j]);
                ins8u(__float_as_uint(k2v[1] + acc[qf][1][j]), cnd[qf][j]);
            }
    }

    // 16-lane bitonic shuffle merge -> per-query top-8 scores
    #pragma unroll
    for (int qf = 0; qf < 2; ++qf)
        #pragma unroll
        for (int j = 0; j < 4; ++j) {
            uint32_t c[8];
            #pragma unroll
            for (int s = 0; s < 8; ++s) c[s] = cnd[qf][j][s];
            #pragma unroll
            for (int mask = 1; mask <= 8; mask <<= 1) {
                uint32_t o[8], m[8];
                #pragma unroll
                for (int s = 0; s < 8; ++s)
                    o[s] = (uint32_t)__shfl_xor((int)c[s], mask, 64);
                #pragma unroll
                for (int s = 0; s < 8; ++s) m[s] = umin32(c[s], o[7 - s]);
                #define CX(a,b) { uint32_t lo = umin32(m[a], m[b]); uint32_t hi = umax32(m[a], m[b]); m[a] = lo; m[b] = hi; }
                CX(0,4) CX(1,5) CX(2,6) CX(3,7)
                CX(0,2) CX(1,3) CX(4,6) CX(5,7)
                CX(0,1) CX(2,3) CX(4,5) CX(6,7)
                #undef CX
                #pragma unroll
                for (int s = 0; s < 8; ++s) c[s] = m[s];
            }
            if (l15 == 0) {
                int q = q0 + w * 32 + qf * 16 + l4 * 4 + j;
                uint32_t* dst = subtop + ((size_t)q * NSUB + sub) * 8;
                uint4 a = {c[0], c[1], c[2], c[3]};
                uint4 b = {c[4], c[5], c[6], c[7]};
                *reinterpret_cast<uint4*>(dst)     = a;
                *reinterpret_cast<uint4*>(dst + 4) = b;
            }
        }
}

// tau: wave-per-query bitonic merge of the NSUB*8 = 128 sample scores ->
// 8th-smallest + margin. 4 queries per 256-thread block.
__global__ __launch_bounds__(256) void tau_kernel(
    const uint32_t* __restrict__ subtop, float* __restrict__ taug,
    uint32_t* __restrict__ ovcnt) {
    const int tid = threadIdx.x, l = tid & 63;
    const int q = blockIdx.x * 4 + (tid >> 6);
    uint32_t a = subtop[(size_t)q * 128 + l];
    uint32_t b = subtop[(size_t)q * 128 + 64 + l];
    uint32_t c[8];
    c[0] = umin32(a, b); c[1] = umax32(a, b);
    #pragma unroll
    for (int s = 2; s < 8; ++s) c[s] = SENTF;
    #pragma unroll
    for (int mask = 1; mask <= 32; mask <<= 1) {
        uint32_t o[8], m[8];
        #pragma unroll
        for (int s = 0; s < 8; ++s)
            o[s] = (uint32_t)__shfl_xor((int)c[s], mask, 64);
        #pragma unroll
        for (int s = 0; s < 8; ++s) m[s] = umin32(c[s], o[7 - s]);
        #define CX(x,y) { uint32_t lo = umin32(m[x], m[y]); uint32_t hi = umax32(m[x], m[y]); m[x] = lo; m[y] = hi; }
        CX(0,4) CX(1,5) CX(2,6) CX(3,7)
        CX(0,2) CX(1,3) CX(4,6) CX(5,7)
        CX(0,1) CX(2,3) CX(4,5) CX(6,7)
        #undef CX
        #pragma unroll
        for (int s = 0; s < 8; ++s) c[s] = m[s];
    }
    if (l == 0) taug[q] = __uint_as_float(c[7]) + TAU_MARGIN;
    if (blockIdx.x == 0 && tid == 0) *ovcnt = 0;
}

// phase 1: MFMA coarse scores, NBUF=2 two-barrier depth-1 counted-vmcnt
// pipeline. 4 waves x 32 queries/wave (2 qfrags x 2 ki). LDS 33.8 KB.
// __launch_bounds__(256,2): allocator assumes 2 waves/EU -> 128-reg budget
// (R17-verified: 88 regs, no spill); RUNTIME occupancy is resource-bound:
// 88 regs + 34 KB LDS -> 4 blocks/CU = 16 waves/CU = 4 waves/SIMD, with 4
// INDEPENDENT blocks so barriers overlap across blocks.
// Ledger: at iter-t wait, outstanding = STAGE(t)+stores(t-1)+STAGE(t+1);
// vmcnt(5) keeps exactly STAGE(t+1). STAGE(t+2) (same buf as t) is issued
// only after barrier-2 = all waves done reading buf[t&1].
__global__ __launch_bounds__(256, 2) void phase1_kernel(
    const unsigned short* __restrict__ qaug, const char* __restrict__ kperm,
    const float* __restrict__ k2, const float* __restrict__ taug,
    uint32_t* __restrict__ list, uint32_t* __restrict__ cnt2,
    uint32_t* __restrict__ ovcnt, unsigned long long* __restrict__ ovlist) {

    __shared__ __align__(16) char     lds[NBUF][TILE_B];   // 32 KiB
    __shared__ __align__(16) float    k2l[NBUF][64];       // 0.5 KiB
    __shared__            uint32_t    scnt[QB];            // 0.5 KiB

    const int tid   = threadIdx.x;
    const int w     = tid >> 6;        // 0..3
    const int l     = tid & 63;
    const int l15   = l & 15;
    const int l4    = l >> 4;
    const int chunk = blockIdx.x & (NCHUNK - 1);
    const int qt    = blockIdx.x >> 6;
    const int q0    = qt * QB;
    const char*  kpb = kperm + (size_t)chunk * ((size_t)CTILES * TILE_B);
    const float* k2c = k2 + (size_t)chunk * CHUNK;

    if (tid < QB) scnt[tid] = 0;   // visible to all waves after iter-0 barrier

    // A fragments: 2 qfrags x 8 steps (wave owns 32 queries)
    bf16x8 af[2][SSTEPS];
    float  tau[2][4];
    #pragma unroll
    for (int qf = 0; qf < 2; ++qf) {
        #pragma unroll
        for (int s = 0; s < SSTEPS; ++s) {
            int qr = q0 + w * 32 + qf * 16 + l15;
            af[qf][s] = *reinterpret_cast<const bf16x8*>(
                qaug + (size_t)qr * KD + s * 32 + l4 * 8);
        }
        #pragma unroll
        for (int j = 0; j < 4; ++j)
            tau[qf][j] = taug[q0 + w * 32 + qf * 16 + l4 * 4 + j];
    }

    // 5 vmem ops per wave per stage (uniform for vmcnt counting)
    auto STAGE = [&](int t) {
        int buf = t & (NBUF - 1);
        const char* src = kpb + (size_t)t * TILE_B;
        #pragma unroll
        for (int i = 0; i < 4; ++i) {
            int seg = w * 4 + i;                       // 16 segs x 1024 B
            gld16(src + seg * 1024 + l * 16, &lds[buf][seg * 1024]);
        }
        gld4(k2c + t * TK + l, &k2l[buf][0]);
    };

    STAGE(0); STAGE(1);

    for (int t = 0; t < CTILES; ++t) {
        const int buf = t & (NBUF - 1);
        // drain tile t's 5 ops (+ older stores); keep STAGE(t+1) in flight
        if (t < CTILES - 1) asm volatile("s_waitcnt vmcnt(5)" ::: "memory");
        else                asm volatile("s_waitcnt vmcnt(0)" ::: "memory");
        __builtin_amdgcn_s_barrier();
        __builtin_amdgcn_sched_barrier(0);

        const char* lb = &lds[buf][0];
        float k2v[2];
        #pragma unroll
        for (int ki = 0; ki < 2; ++ki) k2v[ki] = k2l[buf][ki * 16 + l15] + 256.0f;

        f32x4 acc[2][2];
        #pragma unroll
        for (int qf = 0; qf < 2; ++qf)
            #pragma unroll
            for (int ki = 0; ki < 2; ++ki) acc[qf][ki] = (f32x4){0.f, 0.f, 0.f, 0.f};

        #pragma unroll
        for (int s = 0; s < SSTEPS; ++s) {
            bf16x8 bfr[2];
            #pragma unroll
            for (int ki = 0; ki < 2; ++ki)
                bfr[ki] = *reinterpret_cast<const bf16x8*>(lb + ((s * 2 + ki) * 64 + l) * 16);
            #pragma unroll
            for (int ki = 0; ki < 2; ++ki) {
                acc[0][ki] = __builtin_amdgcn_mfma_f32_16x16x32_bf16(af[0][s], bfr[ki], acc[0][ki], 0, 0, 0);
                acc[1][ki] = __builtin_amdgcn_mfma_f32_16x16x32_bf16(af[1][s], bfr[ki], acc[1][ki], 0, 0, 0);
            }
        }

        const uint32_t kb0 = (uint32_t)(t * TK + l15);   // local key idx (ki=0)
        #pragma unroll
        for (int qf = 0; qf < 2; ++qf)
            #pragma unroll
            for (int ki = 0; ki < 2; ++ki)
                #pragma unroll
                for (int j = 0; j < 4; ++j) {
                    float v0 = k2v[ki] + acc[qf][ki][j];
                    if (v0 < tau[qf][j]) {
                        int ql = w * 32 + qf * 16 + l4 * 4 + j;     // local query
                        uint32_t slot = atomicAdd(&scnt[ql], 1u);   // LDS atomic
                        uint32_t e = (__float_as_uint(v0) & 0xFFFFF800u) | (kb0 + ki * 16u);
                        if (slot < SLOTS) {
                            list[(((size_t)(q0 + ql) * NCHUNK + chunk) << 5) + slot] = e;
                        } else {
                            uint32_t op = atomicAdd(ovcnt, 1u);
                            if (op < OVCAP)
                                ovlist[op] = ((unsigned long long)__float_as_uint(v0) << 32)
                                           | ((unsigned long long)(uint32_t)(q0 + ql) << 17)
                                           | (uint32_t)(chunk * CHUNK + kb0 + ki * 16u);
                        }
                    }
                }

        // barrier 2: all waves done reading buf[t&1]; safe to overwrite it
        __builtin_amdgcn_s_barrier();
        if (t + 2 < CTILES) STAGE(t + 2);
    }

    __syncthreads();   // all waves' LDS atomics done
    if (tid < QB) cnt2[(size_t)(q0 + tid) * NCHUNK + chunk] = umin32(scnt[tid], SLOTS);
}

// phase 2: 4-wave quarter extraction. Wave w owns 16 chunks (512 slots)
// + 16 overflow slots = 528 pool entries (v[9]/lane), extracts its coarse
// top-16 via unique u64 keys (tie-proof). Union (64) is exact-f32 rescored,
// lex top-8, gather.
__global__ __launch_bounds__(256) void phase2_kernel(
    const uint32_t* __restrict__ list, const uint32_t* __restrict__ cnt2,
    const uint32_t* __restrict__ ovcnt, const unsigned long long* __restrict__ ovlist,
    const float* __restrict__ query, const float* __restrict__ keys,
    const float* __restrict__ q2g, const float* __restrict__ k2g,
    const float* __restrict__ vals, float* __restrict__ out) {

    __shared__ uint32_t cc[NCHUNK];
    __shared__ unsigned long long ovq[64];
    __shared__ uint32_t nov;
    __shared__ int topg[64];
    __shared__ float td2[64];
    __shared__ int fin[8];

    const int q = blockIdx.x, tid = threadIdx.x, w = tid >> 6, l = tid & 63;

    if (tid < NCHUNK) cc[tid] = cnt2[(size_t)q * NCHUNK + tid];
    if (tid < 64) ovq[tid] = ~0ull;
    if (tid == 0) nov = 0;
    __syncthreads();
    uint32_t on = umin32(*ovcnt, OVCAP);
    for (uint32_t i = tid; i < on; i += 256) {
        unsigned long long e = ovlist[i];
        if (((e >> 17) & 0x7FFull) == (unsigned long long)q) {
            uint32_t p = atomicAdd(&nov, 1u);
            if (p < 64)
                ovq[p] = ((unsigned long long)((uint32_t)(e >> 32) >> 11) << 17)
                       | (uint32_t)(e & 0x1FFFFull);
        }
    }
    __syncthreads();

    // wave w's pool: chunks [w*16, w*16+16) slots + ovq[w*16 .. w*16+16)
    unsigned long long v[9];
    #pragma unroll
    for (int j = 0; j < 9; ++j) {
        int idx = j * 64 + l;
        unsigned long long key = ~0ull;
        if (idx < 512) {
            int c = w * 16 + (idx >> 5), s = idx & 31;
            if ((uint32_t)s < cc[c]) {
                uint32_t e = list[(((size_t)q * NCHUNK + c) << 5) + s];
                key = ((unsigned long long)(e >> 11) << 17)
                    | (uint32_t)(c * CHUNK + (e & 0x7FFu));
            }
        } else if (idx < 528) {
            key = ovq[w * 16 + (idx - 512)];
        }
        v[j] = key;
    }

    // per-wave coarse top-16 (keys unique -> value-based removal is tie-proof)
    for (int r = 0; r < 16; ++r) {
        unsigned long long bv = v[0];
        #pragma unroll
        for (int j = 1; j < 9; ++j) bv = umin64(bv, v[j]);
        #pragma unroll
        for (int off = 32; off > 0; off >>= 1) {
            unsigned long long ov = __shfl_xor(bv, off, 64);
            bv = umin64(bv, ov);
        }
        if (l == 0) topg[w * 16 + r] = (bv == ~0ull) ? -1 : (int)(uint32_t)(bv & 0x1FFFFull);
        #pragma unroll
        for (int j = 0; j < 9; ++j) if (v[j] == bv) v[j] = ~0ull;
    }
    __syncthreads();

    float4 qv = reinterpret_cast<const float4*>(query + (size_t)q * KD)[l];
    for (int r = w; r < 64; r += 4) {
        int gk = topg[r];
        if (gk >= 0) {
            float4 kv = reinterpret_cast<const float4*>(keys + (size_t)gk * KD)[l];
            float d = qv.x * kv.x + qv.y * kv.y + qv.z * kv.z + qv.w * kv.w;
            #pragma unroll
            for (int off = 32; off > 0; off >>= 1) d += __shfl_down(d, off, 64);
            if (l == 0) td2[r] = fmaxf(q2g[q] + k2g[gk] - 2.0f * d, 0.0f);
        } else if (l == 0) {
            td2[r] = INFINITY;
        }
    }
    __syncthreads();

    if (tid == 0) {
        float fd[8]; int fi[8];
        #pragma unroll
        for (int s = 0; s < 8; ++s) { fd[s] = INFINITY; fi[s] = 0x7fffffff; }
        for (int i = 0; i < 64; ++i) {
            if (topg[i] < 0) continue;
            float d2 = td2[i]; int gk = topg[i];
            if (lex_lt(d2, gk, fd[7], fi[7])) {
                fd[7] = d2; fi[7] = gk;
                #pragma unroll
                for (int p = 7; p > 0; --p)
                    if (lex_lt(fd[p], fi[p], fd[p - 1], fi[p - 1])) {
                        float t1 = fd[p]; fd[p] = fd[p - 1]; fd[p - 1] = t1;
                        int   t2 = fi[p]; fi[p] = fi[p - 1]; fi[p - 1] = t2;
                    }
            }
        }
        #pragma unroll
        for (int s = 0; s < 8; ++s) fin[s] = fi[s];
    }
    __syncthreads();

    for (int r = w; r < TOPK; r += 4) {
        float4 v2 = reinterpret_cast<const float4*>(vals + (size_t)fin[r] * VD)[l];
        reinterpret_cast<float4*>(out + ((size_t)q * TOPK + r) * VD)[l] = v2;
    }
}

extern "C" void kernel_launch(void* const* d_in, const int* in_sizes, int n_in,
                              void* d_out, int out_size, void* d_ws, size_t ws_size,
                              hipStream_t stream) {
    const float* query = (const float*)d_in[0];
    const float* keys  = (const float*)d_in[1];
    const float* vals  = (const float*)d_in[2];
    float* out = (float*)d_out;

    char* ws = (char*)d_ws;
    float*              q2     = (float*)(ws);                       // 8 KB
    float*              k2     = (float*)(ws + 8192);                // 512 KB (+1 KB pad for gld4 tail)
    unsigned short*     qaug   = (unsigned short*)(ws + 533504);     // 1 MB
    unsigned short*     kperm  = (unsigned short*)(ws + 1582080);    // 64 MB
    uint32_t*           list   = (uint32_t*)(ws + 68690944);         // 16 MB
    uint32_t*           subtop = (uint32_t*)(ws + 68690944);         // aliases list (lifetime disjoint)
    uint32_t*           cnt2   = (uint32_t*)(ws + 85468160);         // 512 KB
    float*              taug   = (float*)(ws + 85992448);            // 8 KB
    uint32_t*           ovcnt  = (uint32_t*)(ws + 86000640);         // 4 KB
    unsigned long long* ovlist = (unsigned long long*)(ws + 86004736); // 64 KB (end ~86.1 MB)

    qprep_kernel<<<B_Q / 4, 256, 0, stream>>>(query, q2, qaug);
    kperm2_kernel<<<N_K / 32, 256, 0, stream>>>(keys, kperm, k2);
    sample_kernel<<<(B_Q / QBS) * NSUB, 512, 0, stream>>>(qaug, (const char*)kperm, k2, subtop);
    tau_kernel<<<B_Q / 4, 256, 0, stream>>>(subtop, taug, ovcnt);
    phase1_kernel<<<NCHUNK * QTILES, 256, 0, stream>>>(qaug, (const char*)kperm, k2,
                                                       taug, list, cnt2, ovcnt, ovlist);
    phase2_kernel<<<B_Q, 256, 0, stream>>>(list, cnt2, ovcnt, ovlist,
                                           query, keys, q2, k2, vals, out);
}

// Round 20
// 276.910 us; speedup vs baseline: 1.1843x; 1.1843x over previous
//
#include <hip/hip_runtime.h>
#include <hip/hip_bf16.h>
#include <cstdint>

#define B_Q    2048
#define N_K    131072
#define KD     256
#define VD     256
#define TOPK   8

#define TK     32                 // keys per tile
#define NCHUNK 64
#define CHUNK  (N_K / NCHUNK)     // 2048
#define CTILES (CHUNK / TK)       // 64
#define QB     256                // queries per phase-1 block (16 waves x 16 q)
#define QTILES (B_Q / QB)         // 8
#define QBS    256                // queries per sample block
#define NBUF   4
#define TILE_B (TK * KD * 2)      // 16384 B per permuted tile
#define SSTEPS 8                  // 256 / 32
#define SLOTS  32                 // per-(q,chunk) candidate slots
#define OVCAP  8192
#define NSUB   32                 // sample sub-blocks per query tile (2 tiles each)
#define TAU_MARGIN 2.0f
#define SENTF  0x7F800000u        // +INF bits

typedef short bf16x8 __attribute__((ext_vector_type(8)));
typedef float f32x4  __attribute__((ext_vector_type(4)));

__device__ __forceinline__ unsigned short f2bf(float x) {
    uint32_t u = __float_as_uint(x);
    uint32_t r = (u + 0x7FFFu + ((u >> 16) & 1u)) >> 16;
    return (unsigned short)r;
}

__device__ __forceinline__ bool lex_lt(float d1, int i1, float d2, int i2) {
    return (d1 < d2) || (d1 == d2 && i1 < i2);
}

__device__ __forceinline__ uint32_t umin32(uint32_t a, uint32_t b) { return a < b ? a : b; }
__device__ __forceinline__ uint32_t umax32(uint32_t a, uint32_t b) { return a > b ? a : b; }
__device__ __forceinline__ unsigned long long umin64(unsigned long long a, unsigned long long b) { return a < b ? a : b; }

__device__ __forceinline__ void gld16(const void* g, void* l) {
    __builtin_amdgcn_global_load_lds(
        (const __attribute__((address_space(1))) unsigned int*)g,
        (__attribute__((address_space(3))) unsigned int*)l, 16, 0, 0);
}
__device__ __forceinline__ void gld4(const void* g, void* l) {
    __builtin_amdgcn_global_load_lds(
        (const __attribute__((address_space(1))) unsigned int*)g,
        (__attribute__((address_space(3))) unsigned int*)l, 4, 0, 0);
}

__device__ __forceinline__ void ins8u(uint32_t v, uint32_t (&c)[8]) {
    if (v < c[7]) {
        c[7] = v;
        #pragma unroll
        for (int p = 7; p > 0; --p)
            if (c[p] < c[p - 1]) { uint32_t t = c[p]; c[p] = c[p - 1]; c[p - 1] = t; }
    }
}

// queries: q2 (exact) + augmented bf16 [-2q] rows
__global__ void qprep_kernel(const float* __restrict__ q, float* __restrict__ q2,
                             unsigned short* __restrict__ qa) {
    int gw   = (blockIdx.x * blockDim.x + threadIdx.x) >> 6;
    int lane = threadIdx.x & 63;
    float4 v = reinterpret_cast<const float4*>(q + (size_t)gw * KD)[lane];
    float s = v.x * v.x + v.y * v.y + v.z * v.z + v.w * v.w;
    #pragma unroll
    for (int off = 32; off > 0; off >>= 1) s += __shfl_down(s, off, 64);
    if (lane == 0) q2[gw] = s;
    ushort4 u;
    u.x = f2bf(-2.f * v.x); u.y = f2bf(-2.f * v.y);
    u.z = f2bf(-2.f * v.z); u.w = f2bf(-2.f * v.w);
    *reinterpret_cast<ushort4*>(qa + (size_t)gw * KD + lane * 4) = u;
}

// fused: keys -> k2 (exact row norms) + bf16 permuted MFMA fragment-stream.
__global__ __launch_bounds__(256) void kperm2_kernel(
    const float* __restrict__ keys, unsigned short* __restrict__ kp,
    float* __restrict__ k2) {
    __shared__ float psum[32][33];
    const int gt = blockIdx.x, tid = threadIdx.x;
    #pragma unroll
    for (int u = 0; u < 4; ++u) {
        int unit = u * 256 + tid;
        int row  = unit >> 5;
        int grp  = unit & 31;
        const float* src = keys + (size_t)(gt * 32 + row) * KD + grp * 8;
        float4 a = *reinterpret_cast<const float4*>(src);
        float4 b = *reinterpret_cast<const float4*>(src + 4);
        psum[row][grp] = a.x * a.x + a.y * a.y + a.z * a.z + a.w * a.w
                       + b.x * b.x + b.y * b.y + b.z * b.z + b.w * b.w;
        uint4 pack;
        pack.x = (uint32_t)f2bf(a.x) | ((uint32_t)f2bf(a.y) << 16);
        pack.y = (uint32_t)f2bf(a.z) | ((uint32_t)f2bf(a.w) << 16);
        pack.z = (uint32_t)f2bf(b.x) | ((uint32_t)f2bf(b.y) << 16);
        pack.w = (uint32_t)f2bf(b.z) | ((uint32_t)f2bf(b.w) << 16);
        int s  = grp >> 2;
        int ki = row >> 4;
        int l  = ((grp & 3) << 4) | (row & 15);
        size_t o = ((((size_t)gt * 8 + s) * 2 + ki) * 64 + l);
        *reinterpret_cast<uint4*>(kp + o * 8) = pack;
    }
    __syncthreads();
    if (tid < 32) {
        float s = 0.f;
        #pragma unroll
        for (int g = 0; g < 32; ++g) s += psum[tid][g];
        k2[gt * 32 + tid] = s;
    }
}

// sample: coarse scores (k2+256-2qk) of chunk-0 sub-range (2 tiles = 64 keys),
// per-query top-8 scores -> subtop[q][sub][8] (f32 bits, uint-monotone).
// NSUB=32 -> 256 blocks (full GPU) with a 2-iteration serial chain.
__global__ __launch_bounds__(512, 2) void sample_kernel(
    const unsigned short* __restrict__ qaug, const char* __restrict__ kperm,
    const float* __restrict__ k2, uint32_t* __restrict__ subtop) {

    __shared__ __align__(16) char  lds[TILE_B];
    __shared__ __align__(16) float k2l[64];

    const int tid = threadIdx.x;
    const int w   = tid >> 6;
    const int l   = tid & 63;
    const int l15 = l & 15;
    const int l4  = l >> 4;
    const int sub = blockIdx.x & (NSUB - 1);
    const int qt  = blockIdx.x / NSUB;
    const int q0  = qt * QBS;

    bf16x8 af[2][SSTEPS];
    #pragma unroll
    for (int qf = 0; qf < 2; ++qf)
        #pragma unroll
        for (int s = 0; s < SSTEPS; ++s) {
            int qr = q0 + w * 32 + qf * 16 + l15;
            af[qf][s] = *reinterpret_cast<const bf16x8*>(
                qaug + (size_t)qr * KD + s * 32 + l4 * 8);
        }

    uint32_t cnd[2][4][8];
    #pragma unroll
    for (int qf = 0; qf < 2; ++qf)
        #pragma unroll
        for (int j = 0; j < 4; ++j)
            #pragma unroll
            for (int s = 0; s < 8; ++s) cnd[qf][j][s] = SENTF;

    for (int i = 0; i < 2; ++i) {
        int t = sub * 2 + i;
        __syncthreads();   // prior tile's reads done before overwrite
        const char* src = kperm + (size_t)t * TILE_B;   // chunk 0
        #pragma unroll
        for (int i2 = 0; i2 < 2; ++i2) {
            int seg = w * 2 + i2;
            gld16(src + seg * 1024 + l * 16, &lds[seg * 1024]);
        }
        gld4(k2 + t * TK + l, &k2l[0]);
        __syncthreads();   // drains vmcnt

        float k2v[2];
        #pragma unroll
        for (int ki = 0; ki < 2; ++ki) k2v[ki] = k2l[ki * 16 + l15] + 256.0f;

        f32x4 acc[2][2];
        #pragma unroll
        for (int qf = 0; qf < 2; ++qf)
            #pragma unroll
            for (int ki = 0; ki < 2; ++ki) acc[qf][ki] = (f32x4){0.f, 0.f, 0.f, 0.f};

        #pragma unroll
        for (int s = 0; s < SSTEPS; ++s) {
            bf16x8 bfr[2];
            #pragma unroll
            for (int ki = 0; ki < 2; ++ki)
                bfr[ki] = *reinterpret_cast<const bf16x8*>(&lds[((s * 2 + ki) * 64 + l) * 16]);
            #pragma unroll
            for (int ki = 0; ki < 2; ++ki) {
                acc[0][ki] = __builtin_amdgcn_mfma_f32_16x16x32_bf16(af[0][s], bfr[ki], acc[0][ki], 0, 0, 0);
                acc[1][ki] = __builtin_amdgcn_mfma_f32_16x16x32_bf16(af[1][s], bfr[ki], acc[1][ki], 0, 0, 0);
            }
        }

        #pragma unroll
        for (int qf = 0; qf < 2; ++qf)
            #pragma unroll
            for (int j = 0; j < 4; ++j) {
                ins8u(__float_as_uint(k2v[0] + acc[qf][0][j]), cnd[qf][j]);
                ins8u(__float_as_uint(k2v[1] + acc[qf][1][j]), cnd[qf][j]);
            }
    }

    // 16-lane bitonic shuffle merge -> per-query top-8 scores
    #pragma unroll
    for (int qf = 0; qf < 2; ++qf)
        #pragma unroll
        for (int j = 0; j < 4; ++j) {
            uint32_t c[8];
            #pragma unroll
            for (int s = 0; s < 8; ++s) c[s] = cnd[qf][j][s];
            #pragma unroll
            for (int mask = 1; mask <= 8; mask <<= 1) {
                uint32_t o[8], m[8];
                #pragma unroll
                for (int s = 0; s < 8; ++s)
                    o[s] = (uint32_t)__shfl_xor((int)c[s], mask, 64);
                #pragma unroll
                for (int s = 0; s < 8; ++s) m[s] = umin32(c[s], o[7 - s]);
                #define CX(a,b) { uint32_t lo = umin32(m[a], m[b]); uint32_t hi = umax32(m[a], m[b]); m[a] = lo; m[b] = hi; }
                CX(0,4) CX(1,5) CX(2,6) CX(3,7)
                CX(0,2) CX(1,3) CX(4,6) CX(5,7)
                CX(0,1) CX(2,3) CX(4,5) CX(6,7)
                #undef CX
                #pragma unroll
                for (int s = 0; s < 8; ++s) c[s] = m[s];
            }
            if (l15 == 0) {
                int q = q0 + w * 32 + qf * 16 + l4 * 4 + j;
                uint32_t* dst = subtop + ((size_t)q * NSUB + sub) * 8;
                uint4 a = {c[0], c[1], c[2], c[3]};
                uint4 b = {c[4], c[5], c[6], c[7]};
                *reinterpret_cast<uint4*>(dst)     = a;
                *reinterpret_cast<uint4*>(dst + 4) = b;
            }
        }
}

// tau: wave-per-query bitonic merge of the NSUB*8 = 256 sample scores ->
// 8th-smallest + margin. 4 queries per 256-thread block. Each lane sorts its
// 4 values (5-comparator network), pads to 8, then 6 merge rounds.
__global__ __launch_bounds__(256) void tau_kernel(
    const uint32_t* __restrict__ subtop, float* __restrict__ taug,
    uint32_t* __restrict__ ovcnt) {
    const int tid = threadIdx.x, l = tid & 63;
    const int q = blockIdx.x * 4 + (tid >> 6);
    uint32_t c[8];
    #pragma unroll
    for (int i = 0; i < 4; ++i) c[i] = subtop[(size_t)q * 256 + i * 64 + l];
    #define CS(x,y) { uint32_t lo = umin32(c[x], c[y]); uint32_t hi = umax32(c[x], c[y]); c[x] = lo; c[y] = hi; }
    CS(0,1) CS(2,3) CS(0,2) CS(1,3) CS(1,2)
    #undef CS
    #pragma unroll
    for (int s = 4; s < 8; ++s) c[s] = SENTF;
    #pragma unroll
    for (int mask = 1; mask <= 32; mask <<= 1) {
        uint32_t o[8], m[8];
        #pragma unroll
        for (int s = 0; s < 8; ++s)
            o[s] = (uint32_t)__shfl_xor((int)c[s], mask, 64);
        #pragma unroll
        for (int s = 0; s < 8; ++s) m[s] = umin32(c[s], o[7 - s]);
        #define CX(x,y) { uint32_t lo = umin32(m[x], m[y]); uint32_t hi = umax32(m[x], m[y]); m[x] = lo; m[y] = hi; }
        CX(0,4) CX(1,5) CX(2,6) CX(3,7)
        CX(0,2) CX(1,3) CX(4,6) CX(5,7)
        CX(0,1) CX(2,3) CX(4,5) CX(6,7)
        #undef CX
        #pragma unroll
        for (int s = 0; s < 8; ++s) c[s] = m[s];
    }
    if (l == 0) taug[q] = __uint_as_float(c[7]) + TAU_MARGIN;
    if (blockIdx.x == 0 && tid == 0) *ovcnt = 0;
}

// phase 1 (R12-proven, 188 us): MFMA coarse scores, counted-vmcnt 3-deep
// pipeline, threshold filter. 16 waves x 16 queries/wave (1 q-frag): live
// regs ~90 -> VGPR 48 measured, no spill; 16 waves/CU. Appends via LDS
// counter (ds atomic, lgkmcnt only) + fire-and-forget store.
// Entry u32 = score[31:11] | kloc[10:0] (unique within (q,chunk)).
__global__ __launch_bounds__(1024, 4) void phase1_kernel(
    const unsigned short* __restrict__ qaug, const char* __restrict__ kperm,
    const float* __restrict__ k2, const float* __restrict__ taug,
    uint32_t* __restrict__ list, uint32_t* __restrict__ cnt2,
    uint32_t* __restrict__ ovcnt, unsigned long long* __restrict__ ovlist) {

    __shared__ __align__(16) char     lds[NBUF][TILE_B];   // 64 KiB
    __shared__ __align__(16) float    k2l[NBUF][64];       // 1 KiB
    __shared__            uint32_t    scnt[QB];            // 1 KiB

    const int tid   = threadIdx.x;
    const int w     = tid >> 6;        // 0..15
    const int l     = tid & 63;
    const int l15   = l & 15;
    const int l4    = l >> 4;
    const int chunk = blockIdx.x & (NCHUNK - 1);
    const int qt    = blockIdx.x >> 6;
    const int q0    = qt * QB;
    const char*  kpb = kperm + (size_t)chunk * ((size_t)CTILES * TILE_B);
    const float* k2c = k2 + (size_t)chunk * CHUNK;

    if (tid < QB) scnt[tid] = 0;   // visible to all waves after iter-0 barrier

    // A fragments: 1 qfrag x 8 steps (wave owns 16 queries)
    bf16x8 af[SSTEPS];
    float  tau[4];
    #pragma unroll
    for (int s = 0; s < SSTEPS; ++s) {
        int qr = q0 + w * 16 + l15;
        af[s] = *reinterpret_cast<const bf16x8*>(
            qaug + (size_t)qr * KD + s * 32 + l4 * 8);
    }
    #pragma unroll
    for (int j = 0; j < 4; ++j)
        tau[j] = taug[q0 + w * 16 + l4 * 4 + j];

    // 2 vmem ops per wave per stage (uniform for vmcnt counting)
    auto STAGE = [&](int t) {
        int buf = t & (NBUF - 1);
        const char* src = kpb + (size_t)t * TILE_B;
        gld16(src + w * 1024 + l * 16, &lds[buf][w * 1024]);   // 16 segs x 1024 B
        gld4(k2c + t * TK + l, &k2l[buf][0]);
    };

    STAGE(0); STAGE(1); STAGE(2);

    for (int t = 0; t < CTILES; ++t) {
        const int buf = t & (NBUF - 1);
        if (t < CTILES - 2)       asm volatile("s_waitcnt vmcnt(4)" ::: "memory");
        else if (t == CTILES - 2) asm volatile("s_waitcnt vmcnt(2)" ::: "memory");
        else                      asm volatile("s_waitcnt vmcnt(0)" ::: "memory");
        __builtin_amdgcn_s_barrier();
        __builtin_amdgcn_sched_barrier(0);

        const char* lb = &lds[buf][0];
        float k2v[2];
        #pragma unroll
        for (int ki = 0; ki < 2; ++ki) k2v[ki] = k2l[buf][ki * 16 + l15] + 256.0f;

        f32x4 acc[2];
        #pragma unroll
        for (int ki = 0; ki < 2; ++ki) acc[ki] = (f32x4){0.f, 0.f, 0.f, 0.f};

        #pragma unroll
        for (int s = 0; s < SSTEPS; ++s) {
            bf16x8 bfr[2];
            #pragma unroll
            for (int ki = 0; ki < 2; ++ki)
                bfr[ki] = *reinterpret_cast<const bf16x8*>(lb + ((s * 2 + ki) * 64 + l) * 16);
            #pragma unroll
            for (int ki = 0; ki < 2; ++ki)
                acc[ki] = __builtin_amdgcn_mfma_f32_16x16x32_bf16(af[s], bfr[ki], acc[ki], 0, 0, 0);
        }

        const uint32_t kb = (uint32_t)(t * TK + l15);   // local key idx (ki=0)
        #pragma unroll
        for (int j = 0; j < 4; ++j) {
            float v0 = k2v[0] + acc[0][j];
            float v1 = k2v[1] + acc[1][j];
            float tq = tau[j];
            int   ql = w * 16 + l4 * 4 + j;   // local query idx
            if (v0 < tq) {
                uint32_t slot = atomicAdd(&scnt[ql], 1u);   // LDS atomic
                uint32_t e = (__float_as_uint(v0) & 0xFFFFF800u) | kb;
                if (slot < SLOTS) {
                    list[(((size_t)(q0 + ql) * NCHUNK + chunk) << 5) + slot] = e;
                } else {
                    uint32_t op = atomicAdd(ovcnt, 1u);
                    if (op < OVCAP)
                        ovlist[op] = ((unsigned long long)__float_as_uint(v0) << 32)
                                   | ((unsigned long long)(uint32_t)(q0 + ql) << 17)
                                   | (uint32_t)(chunk * CHUNK + kb);
                }
            }
            if (v1 < tq) {
                uint32_t slot = atomicAdd(&scnt[ql], 1u);
                uint32_t e = (__float_as_uint(v1) & 0xFFFFF800u) | (kb + 16u);
                if (slot < SLOTS) {
                    list[(((size_t)(q0 + ql) * NCHUNK + chunk) << 5) + slot] = e;
                } else {
                    uint32_t op = atomicAdd(ovcnt, 1u);
                    if (op < OVCAP)
                        ovlist[op] = ((unsigned long long)__float_as_uint(v1) << 32)
                                   | ((unsigned long long)(uint32_t)(q0 + ql) << 17)
                                   | (uint32_t)(chunk * CHUNK + kb + 16u);
                }
            }
        }

        if (t + 3 < CTILES) STAGE(t + 3);
    }

    __syncthreads();   // all waves' LDS atomics done
    if (tid < QB) cnt2[(size_t)(q0 + tid) * NCHUNK + chunk] = umin32(scnt[tid], SLOTS);
}

// phase 2: 4-wave quarter extraction. Wave w owns 16 chunks (512 slots)
// + 16 overflow slots = 528 pool entries (v[9]/lane), extracts its coarse
// top-16 via unique u64 keys (tie-proof). Union (64) is exact-f32 rescored,
// lex top-8, gather.
__global__ __launch_bounds__(256) void phase2_kernel(
    const uint32_t* __restrict__ list, const uint32_t* __restrict__ cnt2,
    const uint32_t* __restrict__ ovcnt, const unsigned long long* __restrict__ ovlist,
    const float* __restrict__ query, const float* __restrict__ keys,
    const float* __restrict__ q2g, const float* __restrict__ k2g,
    const float* __restrict__ vals, float* __restrict__ out) {

    __shared__ uint32_t cc[NCHUNK];
    __shared__ unsigned long long ovq[64];
    __shared__ uint32_t nov;
    __shared__ int topg[64];
    __shared__ float td2[64];
    __shared__ int fin[8];

    const int q = blockIdx.x, tid = threadIdx.x, w = tid >> 6, l = tid & 63;

    if (tid < NCHUNK) cc[tid] = cnt2[(size_t)q * NCHUNK + tid];
    if (tid < 64) ovq[tid] = ~0ull;
    if (tid == 0) nov = 0;
    __syncthreads();
    uint32_t on = umin32(*ovcnt, OVCAP);
    for (uint32_t i = tid; i < on; i += 256) {
        unsigned long long e = ovlist[i];
        if (((e >> 17) & 0x7FFull) == (unsigned long long)q) {
            uint32_t p = atomicAdd(&nov, 1u);
            if (p < 64)
                ovq[p] = ((unsigned long long)((uint32_t)(e >> 32) >> 11) << 17)
                       | (uint32_t)(e & 0x1FFFFull);
        }
    }
    __syncthreads();

    // wave w's pool: chunks [w*16, w*16+16) slots + ovq[w*16 .. w*16+16)
    unsigned long long v[9];
    #pragma unroll
    for (int j = 0; j < 9; ++j) {
        int idx = j * 64 + l;
        unsigned long long key = ~0ull;
        if (idx < 512) {
            int c = w * 16 + (idx >> 5), s = idx & 31;
            if ((uint32_t)s < cc[c]) {
                uint32_t e = list[(((size_t)q * NCHUNK + c) << 5) + s];
                key = ((unsigned long long)(e >> 11) << 17)
                    | (uint32_t)(c * CHUNK + (e & 0x7FFu));
            }
        } else if (idx < 528) {
            key = ovq[w * 16 + (idx - 512)];
        }
        v[j] = key;
    }

    // per-wave coarse top-16 (keys unique -> value-based removal is tie-proof)
    for (int r = 0; r < 16; ++r) {
        unsigned long long bv = v[0];
        #pragma unroll
        for (int j = 1; j < 9; ++j) bv = umin64(bv, v[j]);
        #pragma unroll
        for (int off = 32; off > 0; off >>= 1) {
            unsigned long long ov = __shfl_xor(bv, off, 64);
            bv = umin64(bv, ov);
        }
        if (l == 0) topg[w * 16 + r] = (bv == ~0ull) ? -1 : (int)(uint32_t)(bv & 0x1FFFFull);
        #pragma unroll
        for (int j = 0; j < 9; ++j) if (v[j] == bv) v[j] = ~0ull;
    }
    __syncthreads();

    float4 qv = reinterpret_cast<const float4*>(query + (size_t)q * KD)[l];
    for (int r = w; r < 64; r += 4) {
        int gk = topg[r];
        if (gk >= 0) {
            float4 kv = reinterpret_cast<const float4*>(keys + (size_t)gk * KD)[l];
            float d = qv.x * kv.x + qv.y * kv.y + qv.z * kv.z + qv.w * kv.w;
            #pragma unroll
            for (int off = 32; off > 0; off >>= 1) d += __shfl_down(d, off, 64);
            if (l == 0) td2[r] = fmaxf(q2g[q] + k2g[gk] - 2.0f * d, 0.0f);
        } else if (l == 0) {
            td2[r] = INFINITY;
        }
    }
    __syncthreads();

    if (tid == 0) {
        float fd[8]; int fi[8];
        #pragma unroll
        for (int s = 0; s < 8; ++s) { fd[s] = INFINITY; fi[s] = 0x7fffffff; }
        for (int i = 0; i < 64; ++i) {
            if (topg[i] < 0) continue;
            float d2 = td2[i]; int gk = topg[i];
            if (lex_lt(d2, gk, fd[7], fi[7])) {
                fd[7] = d2; fi[7] = gk;
                #pragma unroll
                for (int p = 7; p > 0; --p)
                    if (lex_lt(fd[p], fi[p], fd[p - 1], fi[p - 1])) {
                        float t1 = fd[p]; fd[p] = fd[p - 1]; fd[p - 1] = t1;
                        int   t2 = fi[p]; fi[p] = fi[p - 1]; fi[p - 1] = t2;
                    }
            }
        }
        #pragma unroll
        for (int s = 0; s < 8; ++s) fin[s] = fi[s];
    }
    __syncthreads();

    for (int r = w; r < TOPK; r += 4) {
        float4 v2 = reinterpret_cast<const float4*>(vals + (size_t)fin[r] * VD)[l];
        reinterpret_cast<float4*>(out + ((size_t)q * TOPK + r) * VD)[l] = v2;
    }
}

extern "C" void kernel_launch(void* const* d_in, const int* in_sizes, int n_in,
                              void* d_out, int out_size, void* d_ws, size_t ws_size,
                              hipStream_t stream) {
    const float* query = (const float*)d_in[0];
    const float* keys  = (const float*)d_in[1];
    const float* vals  = (const float*)d_in[2];
    float* out = (float*)d_out;

    char* ws = (char*)d_ws;
    float*              q2     = (float*)(ws);                       // 8 KB
    float*              k2     = (float*)(ws + 8192);                // 512 KB (+1 KB pad for gld4 tail)
    unsigned short*     qaug   = (unsigned short*)(ws + 533504);     // 1 MB
    unsigned short*     kperm  = (unsigned short*)(ws + 1582080);    // 64 MB
    uint32_t*           list   = (uint32_t*)(ws + 68690944);         // 16 MB
    uint32_t*           subtop = (uint32_t*)(ws + 68690944);         // aliases list (lifetime disjoint)
    uint32_t*           cnt2   = (uint32_t*)(ws + 85468160);         // 512 KB
    float*              taug   = (float*)(ws + 85992448);            // 8 KB
    uint32_t*           ovcnt  = (uint32_t*)(ws + 86000640);         // 4 KB
    unsigned long long* ovlist = (unsigned long long*)(ws + 86004736); // 64 KB (end ~86.1 MB)

    qprep_kernel<<<B_Q / 4, 256, 0, stream>>>(query, q2, qaug);
    kperm2_kernel<<<N_K / 32, 256, 0, stream>>>(keys, kperm, k2);
    sample_kernel<<<(B_Q / QBS) * NSUB, 512, 0, stream>>>(qaug, (const char*)kperm, k2, subtop);
    tau_kernel<<<B_Q / 4, 256, 0, stream>>>(subtop, taug, ovcnt);
    phase1_kernel<<<NCHUNK * QTILES, 1024, 0, stream>>>(qaug, (const char*)kperm, k2,
                                                        taug, list, cnt2, ovcnt, ovlist);
    phase2_kernel<<<B_Q, 256, 0, stream>>>(list, cnt2, ovcnt, ovlist,
                                           query, keys, q2, k2, vals, out);
}